// Round 4
// baseline (187.401 us; speedup 1.0000x reference)
//
#include <hip/hip_runtime.h>
#include <hip/hip_bf16.h>
#include <stdint.h>

// ZoeDepth attractor head, R5: wave-autonomous (R4) + FORCED software pipeline.
// R4 post-mortem: VGPR_Count=44 proves hipcc collapsed the rolling prefetch
// (sank loads to uses, minimal-lifetime schedule) => every K-iter exposed
// full memory latency. R5 pins the schedule with sched_barrier(0) after each
// load-issue region, restores the afn/afc w1-frag double buffer (distance-1),
// and keeps a 4-deep upfront x prefetch with in-loop refills. Target VGPR
// ~120 under the launch_bounds(256,4) cap of 128.

#define HW 16384
#define ALPHA 300.0f

typedef short bf16x8_t __attribute__((ext_vector_type(8)));
typedef float f32x4_t __attribute__((ext_vector_type(4)));
typedef unsigned int u32x4_t __attribute__((ext_vector_type(4)));

__device__ __forceinline__ unsigned short f2bf(float f) {
  unsigned int u = __builtin_bit_cast(unsigned int, f);
  u += 0x7fffu + ((u >> 16) & 1u);
  return (unsigned short)(u >> 16);
}
__device__ __forceinline__ unsigned int pack2(float a, float b) {
  return (unsigned int)f2bf(a) | ((unsigned int)f2bf(b) << 16);
}

// ---------------------------------------------------------------------------
// Prep: w1 (128x256) and w2 (16x128) fp32 -> bf16 blobs in frag layout,
// 16B granules XOR-swizzled by (row&3). w1: 8 chunks x 8192 B @0.
// w2: 4 chunks x 1024 B @byte 65536.  (unchanged, verified)
// ---------------------------------------------------------------------------
__global__ void zoed_prep(const float* __restrict__ w1,
                          const float* __restrict__ w2,
                          unsigned short* __restrict__ blob) {
  int i = blockIdx.x * 256 + threadIdx.x;  // 136*256 = 34816 = 32768 + 2048
  if (i < 32768) {
    int o = i >> 8, c = i & 255;
    float v = w1[i];
    int idx = (c >> 5) * 4096 + o * 32 + ((((c >> 3) & 3) ^ (o & 3)) << 3) + (c & 7);
    blob[idx] = f2bf(v);
  } else {
    int i2 = i - 32768;
    int a = i2 >> 7, o = i2 & 127;
    float v = w2[i2];
    int idx = 32768 + (o >> 5) * 512 + a * 32 + ((((o >> 3) & 3) ^ (a & 3)) << 3) + (o & 7);
    blob[idx] = f2bf(v);
  }
}

// ---------------------------------------------------------------------------
// Fused, barrier-free, pinned pipeline. Grid: 1024 blocks x 256 thr.
// Each of the 4 waves owns px [p0, p0+16): GEMM1 (all 128 o), hidden
// transpose via private 4KB LDS, GEMM2, softplus, A-redistribute via private
// 1.25KB LDS, attractor, stores. LDS: hid 4x4096 @0, Abuf 4x1280 @16384.
// ---------------------------------------------------------------------------
__global__ __launch_bounds__(256, 4) void zoed_fused(
    const float* __restrict__ x, const float* __restrict__ bprev,
    const float* __restrict__ b1, const float* __restrict__ b2,
    const unsigned short* __restrict__ wblob, float* __restrict__ out) {
  __shared__ __align__(16) char smem[21504];

  const int t = threadIdx.x;
  const int lane = t & 63;
  const int l15 = lane & 15;
  const int quad = lane >> 4;
  const int wv = t >> 6;
  const int sw = ((quad ^ (l15 & 3)) << 4);

  const int blk = blockIdx.x;
  const int n = blk >> 8;
  const int p0 = ((blk & 255) << 6) + wv * 16;  // this wave's 16-px base

  char* hid = smem + wv * 4096;          // 16px x 128o bf16, frag layout
  char* Ab = smem + 16384 + wv * 1280;   // 16px x 16attr f32, 80B rows

  // x: thread (l15=px, quad=k-subgroup) loads ch = kb*32 + quad*8 + j
  const float* xb = x + (size_t)(n * 256 + quad * 8) * HW + p0 + l15;
  const char* wb = (const char*)wblob + l15 * 64 + sw;

  // ---- prologue: w1 frags chunk 0 FIRST (oldest in queue), then x chunks
  // 0..3 (32 loads). Pin so nothing sinks below. ----
  bf16x8_t afn[8];
#pragma unroll
  for (int tm = 0; tm < 8; tm++)
    afn[tm] = *(const bf16x8_t*)(wb + tm * 1024);

  float xr[4][8];
#pragma unroll
  for (int c = 0; c < 4; c++)
#pragma unroll
    for (int j = 0; j < 8; j++)
      xr[c][j] = xb[(size_t)(c * 32 + j) * HW];
  __builtin_amdgcn_sched_barrier(0);

  // bprev base for this thread's attractor role (quad = bin-group of 16)
  size_t obase = (size_t)(n * 64 + quad * 16) * HW + p0 + l15;
  const float* bp = bprev + obase;
  float bpr[16];

  f32x4_t acc[8];
#pragma unroll
  for (int i = 0; i < 8; i++) acc[i] = (f32x4_t){0.f, 0.f, 0.f, 0.f};

#pragma unroll
  for (int kb = 0; kb < 8; ++kb) {
    // rotate w1-frag double buffer; issue next chunk's frags (distance-1,
    // L2-hot blob)
    bf16x8_t afc[8];
#pragma unroll
    for (int tm = 0; tm < 8; tm++) afc[tm] = afn[tm];
    if (kb < 7) {
#pragma unroll
      for (int tm = 0; tm < 8; tm++)
        afn[tm] = *(const bf16x8_t*)(wb + (kb + 1) * 8192 + tm * 1024);
    }
    // stream bprev under the last GEMM1 iterations
    if (kb == 5) {
#pragma unroll
      for (int b = 0; b < 8; b++) bpr[b] = bp[(size_t)b * HW];
    }
    if (kb == 6) {
#pragma unroll
      for (int b = 8; b < 16; b++) bpr[b] = bp[(size_t)b * HW];
    }
    // pack B-frag from slot kb&3 (s_waitcnt for chunk kb = oldest in queue;
    // younger afn/refill/bpr loads stay in flight)
    u32x4_t v = {pack2(xr[kb & 3][0], xr[kb & 3][1]),
                 pack2(xr[kb & 3][2], xr[kb & 3][3]),
                 pack2(xr[kb & 3][4], xr[kb & 3][5]),
                 pack2(xr[kb & 3][6], xr[kb & 3][7])};
    // refill slot kb&3 with chunk kb+4 (WAR-safe: after pack consumed it)
    if (kb < 4) {
#pragma unroll
      for (int j = 0; j < 8; j++)
        xr[kb & 3][j] = xb[(size_t)((kb + 4) * 32 + j) * HW];
    }
    __builtin_amdgcn_sched_barrier(0);  // pin: loads above stay above
    bf16x8_t bfm = __builtin_bit_cast(bf16x8_t, v);
#pragma unroll
    for (int tm = 0; tm < 8; tm++)
      acc[tm] = __builtin_amdgcn_mfma_f32_16x16x32_bf16(afc[tm], bfm, acc[tm],
                                                        0, 0, 0);
  }

  // w2 frags (L2-hot; latency covered by the hidden epilogue below)
  bf16x8_t a2[4];
#pragma unroll
  for (int kc = 0; kc < 4; kc++)
    a2[kc] = *(const bf16x8_t*)((const char*)wblob + 65536 + kc * 1024 +
                                l15 * 64 + sw);

  // ---- hidden epilogue: relu(acc + b1) -> bf16 -> hid (wave-local) ----
#pragma unroll
  for (int tm = 0; tm < 8; tm++) {
    f32x4_t b1v = *(const f32x4_t*)(b1 + tm * 16 + quad * 4);
    f32x4_t h = acc[tm] + b1v;
    h[0] = fmaxf(h[0], 0.f);
    h[1] = fmaxf(h[1], 0.f);
    h[2] = fmaxf(h[2], 0.f);
    h[3] = fmaxf(h[3], 0.f);
    int kc = tm >> 1;
    int g = (tm & 1) * 2 + (quad >> 1);
    int off8 = (quad & 1) * 8;
    unsigned int* dst = (unsigned int*)(hid + kc * 1024 + l15 * 64 +
                                        ((g ^ (l15 & 3)) << 4) + off8);
    dst[0] = pack2(h[0], h[1]);
    dst[1] = pack2(h[2], h[3]);
  }
  // ---- GEMM2: A(16attr x 16px) = softplus(w2 @ hidden + b2) ----
  // same-wave LDS write->read: lgkmcnt ordering only, no barrier
  f32x4_t acc2 = (f32x4_t){0.f, 0.f, 0.f, 0.f};
#pragma unroll
  for (int kc = 0; kc < 4; kc++) {
    bf16x8_t bh = *(const bf16x8_t*)(hid + kc * 1024 + l15 * 64 + sw);
    acc2 = __builtin_amdgcn_mfma_f32_16x16x32_bf16(a2[kc], bh, acc2, 0, 0, 0);
  }
  {
    f32x4_t b2v = *(const f32x4_t*)(b2 + quad * 4);
    f32x4_t z = acc2 + b2v;
    f32x4_t spv;
#pragma unroll
    for (int r = 0; r < 4; r++) {
      float zz = z[r];
      spv[r] = fmaxf(zz, 0.f) + log1pf(__expf(-fabsf(zz)));  // stable softplus
    }
    // A[attr quad*4+r][px l15] -> Abuf row px (80B stride breaks bank aliasing)
    *(f32x4_t*)(Ab + l15 * 80 + quad * 16) = spv;
  }
  // ---- redistribute: each lane grabs all 16 A of its px (wave-local) ----
  float Av[16];
#pragma unroll
  for (int r = 0; r < 4; r++) {
    f32x4_t v = *(const f32x4_t*)(Ab + l15 * 80 + r * 16);
    Av[r * 4 + 0] = v[0];
    Av[r * 4 + 1] = v[1];
    Av[r * 4 + 2] = v[2];
    Av[r * 4 + 3] = v[3];
  }
  // ---- attractor: lane = (px=l15, bin-group=quad), 16 bins/lane ----
  float* o1 = out + obase;
  float* o2 = o1 + (size_t)256 * HW;
#pragma unroll
  for (int b = 0; b < 16; b++) {
    float c = bpr[b];
    float d0 = 0.f, d1 = 0.f;
#pragma unroll
    for (int a = 0; a < 8; a++) {
      float dx = Av[a] - c;
      float e = __expf(dx * dx * -ALPHA);
      d0 = fmaf(e, dx, d0);
    }
#pragma unroll
    for (int a = 8; a < 16; a++) {
      float dx = Av[a] - c;
      float e = __expf(dx * dx * -ALPHA);
      d1 = fmaf(e, dx, d1);
    }
    float r = c + (d0 + d1);
    __builtin_nontemporal_store(r, o1 + (size_t)b * HW);
    __builtin_nontemporal_store(r, o2 + (size_t)b * HW);
  }
}

extern "C" void kernel_launch(void* const* d_in, const int* in_sizes, int n_in,
                              void* d_out, int out_size, void* d_ws,
                              size_t ws_size, hipStream_t stream) {
  const float* x = (const float*)d_in[0];      // 4*256*128*128
  const float* bprev = (const float*)d_in[1];  // 4*64*128*128
  const float* w1 = (const float*)d_in[2];     // 128*256
  const float* b1 = (const float*)d_in[3];     // 128
  const float* w2 = (const float*)d_in[4];     // 16*128
  const float* b2 = (const float*)d_in[5];     // 16
  float* outp = (float*)d_out;                 // 2 * 4194304
  unsigned short* blob = (unsigned short*)d_ws;  // 69632 B used

  zoed_prep<<<136, 256, 0, stream>>>(w1, w2, blob);
  zoed_fused<<<1024, 256, 0, stream>>>(x, bprev, b1, b2, blob, outp);
}

// Round 5
// 149.797 us; speedup vs baseline: 1.2510x; 1.2510x over previous
//
#include <hip/hip_runtime.h>
#include <hip/hip_bf16.h>
#include <stdint.h>

// ZoeDepth attractor head, R6: wave-autonomous zero-barrier (R4) + VMEM-only
// pinned pipeline. R5 post-mortem: sched_barrier(0) + 128-VGPR cap => regalloc
// meltdown (VGPR=64 + ~100MB scratch traffic in FETCH/WRITE). R6: pins with
// mask 0x78F (only VMEM may not cross), af double-buffer ordered BEFORE x
// refills (in-order vmcnt: MFMA's af-wait then leaves young refills in
// flight), bpr loads moved post-loop (hidden under epilogue), and
// launch_bounds(256,3) -> 170-reg cap, no spill, 3 blocks/CU.

#define HW 16384
#define ALPHA 300.0f
// sched_barrier mask: ALU|VALU|SALU|MFMA|DS|DSread|DSwrite|TRANS may cross;
// VMEM (0x10|0x20|0x40) may NOT.
#define PIN_VMEM() __builtin_amdgcn_sched_barrier(0x78F)

typedef short bf16x8_t __attribute__((ext_vector_type(8)));
typedef float f32x4_t __attribute__((ext_vector_type(4)));
typedef unsigned int u32x4_t __attribute__((ext_vector_type(4)));

__device__ __forceinline__ unsigned short f2bf(float f) {
  unsigned int u = __builtin_bit_cast(unsigned int, f);
  u += 0x7fffu + ((u >> 16) & 1u);
  return (unsigned short)(u >> 16);
}
__device__ __forceinline__ unsigned int pack2(float a, float b) {
  return (unsigned int)f2bf(a) | ((unsigned int)f2bf(b) << 16);
}

// ---------------------------------------------------------------------------
// Prep: w1 (128x256) and w2 (16x128) fp32 -> bf16 blobs in frag layout,
// 16B granules XOR-swizzled by (row&3). w1: 8 chunks x 8192 B @0.
// w2: 4 chunks x 1024 B @byte 65536.  (unchanged, verified)
// ---------------------------------------------------------------------------
__global__ void zoed_prep(const float* __restrict__ w1,
                          const float* __restrict__ w2,
                          unsigned short* __restrict__ blob) {
  int i = blockIdx.x * 256 + threadIdx.x;  // 136*256 = 34816 = 32768 + 2048
  if (i < 32768) {
    int o = i >> 8, c = i & 255;
    float v = w1[i];
    int idx = (c >> 5) * 4096 + o * 32 + ((((c >> 3) & 3) ^ (o & 3)) << 3) + (c & 7);
    blob[idx] = f2bf(v);
  } else {
    int i2 = i - 32768;
    int a = i2 >> 7, o = i2 & 127;
    float v = w2[i2];
    int idx = 32768 + (o >> 5) * 512 + a * 32 + ((((o >> 3) & 3) ^ (a & 3)) << 3) + (o & 7);
    blob[idx] = f2bf(v);
  }
}

// ---------------------------------------------------------------------------
// Fused, barrier-free, VMEM-pinned pipeline. Grid: 1024 blocks x 256 thr.
// Each of the 4 waves owns px [p0, p0+16): GEMM1 (all 128 o), hidden
// transpose via private 4KB LDS, GEMM2, softplus, A-redistribute via private
// 1.25KB LDS, attractor, stores. LDS: hid 4x4096 @0, Abuf 4x1280 @16384.
// ---------------------------------------------------------------------------
__global__ __launch_bounds__(256, 3) void zoed_fused(
    const float* __restrict__ x, const float* __restrict__ bprev,
    const float* __restrict__ b1, const float* __restrict__ b2,
    const unsigned short* __restrict__ wblob, float* __restrict__ out) {
  __shared__ __align__(16) char smem[21504];

  const int t = threadIdx.x;
  const int lane = t & 63;
  const int l15 = lane & 15;
  const int quad = lane >> 4;
  const int wv = t >> 6;
  const int sw = ((quad ^ (l15 & 3)) << 4);

  const int blk = blockIdx.x;
  const int n = blk >> 8;
  const int p0 = ((blk & 255) << 6) + wv * 16;  // this wave's 16-px base

  char* hid = smem + wv * 4096;          // 16px x 128o bf16, frag layout
  char* Ab = smem + 16384 + wv * 1280;   // 16px x 16attr f32, 80B rows

  // x: thread (l15=px, quad=k-subgroup) loads ch = kb*32 + quad*8 + j
  const float* xb = x + (size_t)(n * 256 + quad * 8) * HW + p0 + l15;
  const char* wb = (const char*)wblob + l15 * 64 + sw;

  // ---- prologue: af chunk 0 FIRST (oldest), then x chunks 0..2. Pin. ----
  bf16x8_t af[2][8];  // static-indexed double buffer (kb fully unrolled)
#pragma unroll
  for (int tm = 0; tm < 8; tm++)
    af[0][tm] = *(const bf16x8_t*)(wb + tm * 1024);

  float xr[4][8];
#pragma unroll
  for (int c = 0; c < 3; c++)
#pragma unroll
    for (int j = 0; j < 8; j++)
      xr[c][j] = xb[(size_t)(c * 32 + j) * HW];
  PIN_VMEM();

  f32x4_t acc[8];
#pragma unroll
  for (int i = 0; i < 8; i++) acc[i] = (f32x4_t){0.f, 0.f, 0.f, 0.f};

#pragma unroll
  for (int kb = 0; kb < 8; ++kb) {
    // (1) next chunk's w1 frags — issued BEFORE this iter's x refill so the
    // next MFMA's af-wait leaves young x refills outstanding (in-order vmcnt)
    if (kb < 7) {
#pragma unroll
      for (int tm = 0; tm < 8; tm++)
        af[(kb + 1) & 1][tm] =
            *(const bf16x8_t*)(wb + (kb + 1) * 8192 + tm * 1024);
    }
    PIN_VMEM();
    // (2) x refill: chunk kb+3 into slot (kb+3)&3 (distance-3 prefetch)
    if (kb < 5) {
#pragma unroll
      for (int j = 0; j < 8; j++)
        xr[(kb + 3) & 3][j] = xb[(size_t)((kb + 3) * 32 + j) * HW];
    }
    PIN_VMEM();
    // (3) pack B-frag from slot kb&3 (its chunk was forced complete by the
    // previous iter's af-wait; effectively zero stall here)
    u32x4_t v = {pack2(xr[kb & 3][0], xr[kb & 3][1]),
                 pack2(xr[kb & 3][2], xr[kb & 3][3]),
                 pack2(xr[kb & 3][4], xr[kb & 3][5]),
                 pack2(xr[kb & 3][6], xr[kb & 3][7])};
    bf16x8_t bfm = __builtin_bit_cast(bf16x8_t, v);
#pragma unroll
    for (int tm = 0; tm < 8; tm++)
      acc[tm] = __builtin_amdgcn_mfma_f32_16x16x32_bf16(af[kb & 1][tm], bfm,
                                                        acc[tm], 0, 0, 0);
  }

  // ---- post-loop loads: bprev (16) then w2 frags (4); pin so they issue
  // here and their latency hides under the epilogue VALU work ----
  size_t obase = (size_t)(n * 64 + quad * 16) * HW + p0 + l15;
  const float* bp = bprev + obase;
  float bpr[16];
#pragma unroll
  for (int b = 0; b < 16; b++) bpr[b] = bp[(size_t)b * HW];
  bf16x8_t a2[4];
#pragma unroll
  for (int kc = 0; kc < 4; kc++)
    a2[kc] = *(const bf16x8_t*)((const char*)wblob + 65536 + kc * 1024 +
                                l15 * 64 + sw);
  PIN_VMEM();

  // ---- hidden epilogue: relu(acc + b1) -> bf16 -> hid (wave-local) ----
#pragma unroll
  for (int tm = 0; tm < 8; tm++) {
    f32x4_t b1v = *(const f32x4_t*)(b1 + tm * 16 + quad * 4);
    f32x4_t h = acc[tm] + b1v;
    h[0] = fmaxf(h[0], 0.f);
    h[1] = fmaxf(h[1], 0.f);
    h[2] = fmaxf(h[2], 0.f);
    h[3] = fmaxf(h[3], 0.f);
    int kc = tm >> 1;
    int g = (tm & 1) * 2 + (quad >> 1);
    int off8 = (quad & 1) * 8;
    unsigned int* dst = (unsigned int*)(hid + kc * 1024 + l15 * 64 +
                                        ((g ^ (l15 & 3)) << 4) + off8);
    dst[0] = pack2(h[0], h[1]);
    dst[1] = pack2(h[2], h[3]);
  }
  // ---- GEMM2: A(16attr x 16px) = softplus(w2 @ hidden + b2) ----
  // same-wave LDS write->read: lgkmcnt ordering only, no barrier
  f32x4_t acc2 = (f32x4_t){0.f, 0.f, 0.f, 0.f};
#pragma unroll
  for (int kc = 0; kc < 4; kc++) {
    bf16x8_t bh = *(const bf16x8_t*)(hid + kc * 1024 + l15 * 64 + sw);
    acc2 = __builtin_amdgcn_mfma_f32_16x16x32_bf16(a2[kc], bh, acc2, 0, 0, 0);
  }
  {
    f32x4_t b2v = *(const f32x4_t*)(b2 + quad * 4);
    f32x4_t z = acc2 + b2v;
    f32x4_t spv;
#pragma unroll
    for (int r = 0; r < 4; r++) {
      float zz = z[r];
      spv[r] = fmaxf(zz, 0.f) + log1pf(__expf(-fabsf(zz)));  // stable softplus
    }
    // A[attr quad*4+r][px l15] -> Abuf row px (80B stride breaks bank aliasing)
    *(f32x4_t*)(Ab + l15 * 80 + quad * 16) = spv;
  }
  // ---- redistribute: each lane grabs all 16 A of its px (wave-local) ----
  float Av[16];
#pragma unroll
  for (int r = 0; r < 4; r++) {
    f32x4_t v = *(const f32x4_t*)(Ab + l15 * 80 + r * 16);
    Av[r * 4 + 0] = v[0];
    Av[r * 4 + 1] = v[1];
    Av[r * 4 + 2] = v[2];
    Av[r * 4 + 3] = v[3];
  }
  // ---- attractor: lane = (px=l15, bin-group=quad), 16 bins/lane ----
  float* o1 = out + obase;
  float* o2 = o1 + (size_t)256 * HW;
#pragma unroll
  for (int b = 0; b < 16; b++) {
    float c = bpr[b];
    float d0 = 0.f, d1 = 0.f;
#pragma unroll
    for (int a = 0; a < 8; a++) {
      float dx = Av[a] - c;
      float e = __expf(dx * dx * -ALPHA);
      d0 = fmaf(e, dx, d0);
    }
#pragma unroll
    for (int a = 8; a < 16; a++) {
      float dx = Av[a] - c;
      float e = __expf(dx * dx * -ALPHA);
      d1 = fmaf(e, dx, d1);
    }
    float r = c + (d0 + d1);
    __builtin_nontemporal_store(r, o1 + (size_t)b * HW);
    __builtin_nontemporal_store(r, o2 + (size_t)b * HW);
  }
}

extern "C" void kernel_launch(void* const* d_in, const int* in_sizes, int n_in,
                              void* d_out, int out_size, void* d_ws,
                              size_t ws_size, hipStream_t stream) {
  const float* x = (const float*)d_in[0];      // 4*256*128*128
  const float* bprev = (const float*)d_in[1];  // 4*64*128*128
  const float* w1 = (const float*)d_in[2];     // 128*256
  const float* b1 = (const float*)d_in[3];     // 128
  const float* w2 = (const float*)d_in[4];     // 16*128
  const float* b2 = (const float*)d_in[5];     // 16
  float* outp = (float*)d_out;                 // 2 * 4194304
  unsigned short* blob = (unsigned short*)d_ws;  // 69632 B used

  zoed_prep<<<136, 256, 0, stream>>>(w1, w2, blob);
  zoed_fused<<<1024, 256, 0, stream>>>(x, bprev, b1, b2, blob, outp);
}

// Round 6
// 140.922 us; speedup vs baseline: 1.3298x; 1.0630x over previous
//
#include <hip/hip_runtime.h>
#include <hip/hip_bf16.h>
#include <stdint.h>

// ZoeDepth attractor head, R7: wave-autonomous zero-barrier (R4) + INLINE-ASM
// load pipeline. R5/R6 post-mortem: both sched_barrier pin strategies were
// defeated (VGPR 44/48 = loads sunk to uses; R5 additionally spilled). The
// only ordering hipcc cannot undo is volatile-asm program order. R7 issues
// every K-loop global load as asm volatile (x: global_load_dword; w1 frags:
// global_load_dwordx4 from contiguous blob granules) and waits with
// hand-counted s_waitcnt vmcnt(N) (in-order completion; N={32,24,24,24,24,
// 16,8,0}), each followed by sched_barrier(0) per rule 18. Compiler loads
// (bprev/w2/b1/b2) only after the asm queue drains to 0. launch_bounds(256,3).

#define HW 16384
#define ALPHA 300.0f

typedef short bf16x8_t __attribute__((ext_vector_type(8)));
typedef float f32x4_t __attribute__((ext_vector_type(4)));
typedef unsigned int u32x4_t __attribute__((ext_vector_type(4)));

__device__ __forceinline__ unsigned short f2bf(float f) {
  unsigned int u = __builtin_bit_cast(unsigned int, f);
  u += 0x7fffu + ((u >> 16) & 1u);
  return (unsigned short)(u >> 16);
}
__device__ __forceinline__ unsigned int pack2(float a, float b) {
  return (unsigned int)f2bf(a) | ((unsigned int)f2bf(b) << 16);
}
// volatile-asm loads: program-order issue, no compiler waitcnt tracking
__device__ __forceinline__ float ald(const float* p) {
  float r;
  asm volatile("global_load_dword %0, %1, off" : "=v"(r) : "v"(p));
  return r;
}
__device__ __forceinline__ u32x4_t ald4(const void* p) {
  u32x4_t r;
  asm volatile("global_load_dwordx4 %0, %1, off" : "=v"(r) : "v"(p));
  return r;
}

// ---------------------------------------------------------------------------
// Prep: w1 (128x256) and w2 (16x128) fp32 -> bf16 blobs in frag layout,
// 16B granules XOR-swizzled by (row&3). w1: 8 chunks x 8192 B @0.
// w2: 4 chunks x 1024 B @byte 65536.  (unchanged, verified)
// ---------------------------------------------------------------------------
__global__ void zoed_prep(const float* __restrict__ w1,
                          const float* __restrict__ w2,
                          unsigned short* __restrict__ blob) {
  int i = blockIdx.x * 256 + threadIdx.x;  // 136*256 = 34816 = 32768 + 2048
  if (i < 32768) {
    int o = i >> 8, c = i & 255;
    float v = w1[i];
    int idx = (c >> 5) * 4096 + o * 32 + ((((c >> 3) & 3) ^ (o & 3)) << 3) + (c & 7);
    blob[idx] = f2bf(v);
  } else {
    int i2 = i - 32768;
    int a = i2 >> 7, o = i2 & 127;
    float v = w2[i2];
    int idx = 32768 + (o >> 5) * 512 + a * 32 + ((((o >> 3) & 3) ^ (a & 3)) << 3) + (o & 7);
    blob[idx] = f2bf(v);
  }
}

// One pipelined K-iteration. Issue order (volatile asm): AF(kb+1) then
// X(kb+3); then s_waitcnt vmcnt(NWAIT) covers AF(kb)+X(kb) (in-order),
// leaving younger chunk-groups in flight; sched_barrier(0) fences the
// register-only consumers (rule 18); then pack + 8 MFMA.
#define KITER(KB, NWAIT, AFNEXT, XNEXT)                                     \
  {                                                                         \
    constexpr int kb = KB;                                                  \
    if (AFNEXT) {                                                           \
      _Pragma("unroll") for (int tm = 0; tm < 8; tm++)                      \
          af[(kb + 1) & 1][tm] = ald4(wb + (kb + 1) * 8192 + tm * 1024);    \
    }                                                                       \
    if (XNEXT) {                                                            \
      _Pragma("unroll") for (int j = 0; j < 8; j++)                         \
          xr[(kb + 3) & 3][j] = ald(xb + (size_t)((kb + 3) * 32 + j) * HW); \
    }                                                                       \
    asm volatile("s_waitcnt vmcnt(" #NWAIT ")");                            \
    __builtin_amdgcn_sched_barrier(0);                                      \
    u32x4_t v = {pack2(xr[kb & 3][0], xr[kb & 3][1]),                       \
                 pack2(xr[kb & 3][2], xr[kb & 3][3]),                       \
                 pack2(xr[kb & 3][4], xr[kb & 3][5]),                       \
                 pack2(xr[kb & 3][6], xr[kb & 3][7])};                      \
    bf16x8_t bfm = __builtin_bit_cast(bf16x8_t, v);                         \
    _Pragma("unroll") for (int tm = 0; tm < 8; tm++)                        \
        acc[tm] = __builtin_amdgcn_mfma_f32_16x16x32_bf16(                  \
            __builtin_bit_cast(bf16x8_t, af[kb & 1][tm]), bfm, acc[tm], 0,  \
            0, 0);                                                          \
  }

// ---------------------------------------------------------------------------
// Fused, barrier-free, asm-pipelined. Grid: 1024 blocks x 256 thr.
// Each of the 4 waves owns px [p0, p0+16): GEMM1 (all 128 o), hidden
// transpose via private 4KB LDS, GEMM2, softplus, A-redistribute via private
// 1.25KB LDS, attractor, stores. LDS: hid 4x4096 @0, Abuf 4x1280 @16384.
// ---------------------------------------------------------------------------
__global__ __launch_bounds__(256, 3) void zoed_fused(
    const float* __restrict__ x, const float* __restrict__ bprev,
    const float* __restrict__ b1, const float* __restrict__ b2,
    const unsigned short* __restrict__ wblob, float* __restrict__ out) {
  __shared__ __align__(16) char smem[21504];

  const int t = threadIdx.x;
  const int lane = t & 63;
  const int l15 = lane & 15;
  const int quad = lane >> 4;
  const int wv = t >> 6;
  const int sw = ((quad ^ (l15 & 3)) << 4);

  const int blk = blockIdx.x;
  const int n = blk >> 8;
  const int p0 = ((blk & 255) << 6) + wv * 16;  // this wave's 16-px base

  char* hid = smem + wv * 4096;          // 16px x 128o bf16, frag layout
  char* Ab = smem + 16384 + wv * 1280;   // 16px x 16attr f32, 80B rows

  // x: thread (l15=px, quad=k-subgroup) loads ch = kb*32 + quad*8 + j
  const float* xb = x + (size_t)(n * 256 + quad * 8) * HW + p0 + l15;
  const char* wb = (const char*)wblob + l15 * 64 + sw;

  // ---- prologue (issue order fixed by volatile asm):
  // AF0 [8], X0 X1 X2 [24] -> 32 outstanding ----
  u32x4_t af[2][8];
#pragma unroll
  for (int tm = 0; tm < 8; tm++) af[0][tm] = ald4(wb + tm * 1024);
  float xr[4][8];
#pragma unroll
  for (int c = 0; c < 3; c++)
#pragma unroll
    for (int j = 0; j < 8; j++)
      xr[c][j] = ald(xb + (size_t)(c * 32 + j) * HW);

  f32x4_t acc[8];
#pragma unroll
  for (int i = 0; i < 8; i++) acc[i] = (f32x4_t){0.f, 0.f, 0.f, 0.f};

  // Issue sequence: AF0 X0 X1 X2 | AF1 X3 | AF2 X4 | AF3 X5 | AF4 X6 |
  // AF5 X7 | AF6 | AF7.  Waits (in-order vmcnt, need AF(kb)+X(kb)):
  KITER(0, 32, 1, 1)
  KITER(1, 24, 1, 1)
  KITER(2, 24, 1, 1)
  KITER(3, 24, 1, 1)
  KITER(4, 24, 1, 1)
  KITER(5, 16, 1, 0)
  KITER(6, 8, 1, 0)
  KITER(7, 0, 0, 0)
  // queue drained (vmcnt 0): compiler-generated loads are safe from here on

  // ---- post-loop loads: bprev (16) + w2 frags (4); latency hides under
  // the epilogue VALU work ----
  size_t obase = (size_t)(n * 64 + quad * 16) * HW + p0 + l15;
  const float* bp = bprev + obase;
  float bpr[16];
#pragma unroll
  for (int b = 0; b < 16; b++) bpr[b] = bp[(size_t)b * HW];
  bf16x8_t a2[4];
#pragma unroll
  for (int kc = 0; kc < 4; kc++)
    a2[kc] = *(const bf16x8_t*)((const char*)wblob + 65536 + kc * 1024 +
                                l15 * 64 + sw);

  // ---- hidden epilogue: relu(acc + b1) -> bf16 -> hid (wave-local) ----
#pragma unroll
  for (int tm = 0; tm < 8; tm++) {
    f32x4_t b1v = *(const f32x4_t*)(b1 + tm * 16 + quad * 4);
    f32x4_t h = acc[tm] + b1v;
    h[0] = fmaxf(h[0], 0.f);
    h[1] = fmaxf(h[1], 0.f);
    h[2] = fmaxf(h[2], 0.f);
    h[3] = fmaxf(h[3], 0.f);
    int kc = tm >> 1;
    int g = (tm & 1) * 2 + (quad >> 1);
    int off8 = (quad & 1) * 8;
    unsigned int* dst = (unsigned int*)(hid + kc * 1024 + l15 * 64 +
                                        ((g ^ (l15 & 3)) << 4) + off8);
    dst[0] = pack2(h[0], h[1]);
    dst[1] = pack2(h[2], h[3]);
  }
  // ---- GEMM2: A(16attr x 16px) = softplus(w2 @ hidden + b2) ----
  // same-wave LDS write->read: lgkmcnt ordering only, no barrier
  f32x4_t acc2 = (f32x4_t){0.f, 0.f, 0.f, 0.f};
#pragma unroll
  for (int kc = 0; kc < 4; kc++) {
    bf16x8_t bh = *(const bf16x8_t*)(hid + kc * 1024 + l15 * 64 + sw);
    acc2 = __builtin_amdgcn_mfma_f32_16x16x32_bf16(a2[kc], bh, acc2, 0, 0, 0);
  }
  {
    f32x4_t b2v = *(const f32x4_t*)(b2 + quad * 4);
    f32x4_t z = acc2 + b2v;
    f32x4_t spv;
#pragma unroll
    for (int r = 0; r < 4; r++) {
      float zz = z[r];
      spv[r] = fmaxf(zz, 0.f) + log1pf(__expf(-fabsf(zz)));  // stable softplus
    }
    // A[attr quad*4+r][px l15] -> Abuf row px (80B stride breaks bank aliasing)
    *(f32x4_t*)(Ab + l15 * 80 + quad * 16) = spv;
  }
  // ---- redistribute: each lane grabs all 16 A of its px (wave-local) ----
  float Av[16];
#pragma unroll
  for (int r = 0; r < 4; r++) {
    f32x4_t v = *(const f32x4_t*)(Ab + l15 * 80 + r * 16);
    Av[r * 4 + 0] = v[0];
    Av[r * 4 + 1] = v[1];
    Av[r * 4 + 2] = v[2];
    Av[r * 4 + 3] = v[3];
  }
  // ---- attractor: lane = (px=l15, bin-group=quad), 16 bins/lane ----
  float* o1 = out + obase;
  float* o2 = o1 + (size_t)256 * HW;
#pragma unroll
  for (int b = 0; b < 16; b++) {
    float c = bpr[b];
    float d0 = 0.f, d1 = 0.f;
#pragma unroll
    for (int a = 0; a < 8; a++) {
      float dx = Av[a] - c;
      float e = __expf(dx * dx * -ALPHA);
      d0 = fmaf(e, dx, d0);
    }
#pragma unroll
    for (int a = 8; a < 16; a++) {
      float dx = Av[a] - c;
      float e = __expf(dx * dx * -ALPHA);
      d1 = fmaf(e, dx, d1);
    }
    float r = c + (d0 + d1);
    __builtin_nontemporal_store(r, o1 + (size_t)b * HW);
    __builtin_nontemporal_store(r, o2 + (size_t)b * HW);
  }
}

extern "C" void kernel_launch(void* const* d_in, const int* in_sizes, int n_in,
                              void* d_out, int out_size, void* d_ws,
                              size_t ws_size, hipStream_t stream) {
  const float* x = (const float*)d_in[0];      // 4*256*128*128
  const float* bprev = (const float*)d_in[1];  // 4*64*128*128
  const float* w1 = (const float*)d_in[2];     // 128*256
  const float* b1 = (const float*)d_in[3];     // 128
  const float* w2 = (const float*)d_in[4];     // 16*128
  const float* b2 = (const float*)d_in[5];     // 16
  float* outp = (float*)d_out;                 // 2 * 4194304
  unsigned short* blob = (unsigned short*)d_ws;  // 69632 B used

  zoed_prep<<<136, 256, 0, stream>>>(w1, w2, blob);
  zoed_fused<<<1024, 256, 0, stream>>>(x, bprev, b1, b2, blob, outp);
}